// Round 10
// baseline (1349.049 us; speedup 1.0000x reference)
//
#include <hip/hip_runtime.h>

// SNN: 3-layer LIF, 100 timesteps, ONE persistent kernel, bit-exact fp32
// numpy semantics (rounds 6/8 passed with absmax 0.0):
//  - LIF update: separate mul/add/sub roundings (__f*_rn, no contraction)
//  - spk1@W2: k-ascending chain from 0, bias AFTER. Spikes as floats
//    {0.0f,1.0f}; acc = fmaf(spk,w,acc) bit-identical to conditional fadd.
//  - x@W1 (K=2): fma(x1,w1b, round(x0*w1a)) + b1
//  - spk2@W3: fp64 tree reduce (no downstream nonlinearity)
// Round 9 vs 8: addressing-clean inner loop. Round-8 counters showed ~3 VALU
// instr per fmac (2.45M cy/SIMD vs 0.82M fmac floor) -- address arithmetic.
// Pointer-walk W2 (const offsets 0/1K/2K/3K + one ptr bump per kg) and flat
// LDS indexing (r*1024 -> ds offset immediate) cut overhead to ~1.1x fmac.

#define NB     4096
#define NH     256
#define NSTEPS 100
#define RPB    8    // batch rows per block -> 512 blocks, 2 per CU

__global__ __launch_bounds__(256) void snn_fused(
    const float* __restrict__ x,
    const float* __restrict__ W1,
    const float* __restrict__ b1,
    const float* __restrict__ W2,
    const float* __restrict__ b2,
    const float* __restrict__ W3,
    const float* __restrict__ b3,
    float* __restrict__ out)
{
    const int t    = threadIdx.x;          // 0..255, = hidden unit index
    const int wave = t >> 6, lane = t & 63;
    const int r0   = blockIdx.x * RPB;

    __shared__ float  spks[RPB * NH];  // layer-1 spikes as floats (8 KB), flat
    __shared__ double red[RPB][4];     // output reduction scratch

    const float  w1a = W1[t];        // W1[0][t]
    const float  w1b = W1[NH + t];   // W1[1][t]
    const float  b1t = b1[t];
    const float  b2t = b2[t];
    const double w3t = (double)W3[t];

    float cur1[RPB], mem1[RPB], mem2[RPB], spk2[RPB];
    #pragma unroll
    for (int r = 0; r < RPB; ++r) {
        const float x0 = x[(r0 + r) * 2 + 0];
        const float x1 = x[(r0 + r) * 2 + 1];
        cur1[r] = __fadd_rn(__fmaf_rn(x1, w1b, __fmul_rn(x0, w1a)), b1t);
        mem1[r] = 0.0f;
        mem2[r] = 0.0f;
        spk2[r] = 0.0f;
    }

    for (int step = 0; step < NSTEPS; ++step) {
        // ---- layer 1 LIF (strict fp32 rounding order); spikes -> LDS floats
        #pragma unroll
        for (int r = 0; r < RPB; ++r) {
            float m   = mem1[r];
            float rst = (m > 1.0f) ? 1.0f : 0.0f;
            m = __fsub_rn(__fadd_rn(__fmul_rn(0.9f, m), cur1[r]), rst);
            mem1[r] = m;
            spks[r * NH + t] = (m > 1.0f) ? 1.0f : 0.0f;
        }
        __syncthreads();

        // ---- layer 2 current: k-ascending fmac chain (== BLAS, bit-exact)
        float acc[RPB];
        #pragma unroll
        for (int r = 0; r < RPB; ++r) acc[r] = 0.0f;

        const float* wp = W2 + t;      // walks down column t, 4 rows/iter
        const float* sp = spks;        // flat LDS base
        #pragma unroll 1
        for (int kg = 0; kg < NH / 4; ++kg) {
            // 4 W2 values: compile-time offsets 0/1024/2048/3072 B, then bump
            const float w0 = wp[0 * NH];
            const float w1 = wp[1 * NH];
            const float w2v = wp[2 * NH];
            const float w3v = wp[3 * NH];
            wp += 4 * NH;
            // 8 broadcast float4 spike reads: r*1024 B -> ds offset immediate
            #pragma unroll
            for (int r = 0; r < RPB; ++r) {
                const float4 s = *(const float4*)(sp + r * NH);
                float a = acc[r];
                a = __fmaf_rn(s.x, w0,  a);
                a = __fmaf_rn(s.y, w1,  a);
                a = __fmaf_rn(s.z, w2v, a);
                a = __fmaf_rn(s.w, w3v, a);
                acc[r] = a;
            }
            sp += 4;
        }

        // ---- layer 2 LIF (bias AFTER the chain, strict rounding) ----
        #pragma unroll
        for (int r = 0; r < RPB; ++r) {
            float c2  = __fadd_rn(acc[r], b2t);
            float m   = mem2[r];
            float rst = (m > 1.0f) ? 1.0f : 0.0f;
            m = __fsub_rn(__fadd_rn(__fmul_rn(0.9f, m), c2), rst);
            mem2[r] = m;
            spk2[r] = (m > 1.0f) ? 1.0f : 0.0f;   // only final step survives
        }
        __syncthreads();   // protect spks before next step's writes
    }

    // ---- output: out[b] = sum_j spk2[b][j]*W3[j] + b3 (fp64 tree) ----
    #pragma unroll
    for (int r = 0; r < RPB; ++r) {
        double v = (double)spk2[r] * w3t;
        #pragma unroll
        for (int off = 32; off > 0; off >>= 1)
            v += __shfl_down(v, off);   // wave64
        if (lane == 0) red[r][wave] = v;
    }
    __syncthreads();
    if (t < RPB) {
        out[r0 + t] = (float)(red[t][0] + red[t][1] + red[t][2] + red[t][3]
                              + (double)b3[0]);
    }
}

extern "C" void kernel_launch(void* const* d_in, const int* in_sizes, int n_in,
                              void* d_out, int out_size, void* d_ws, size_t ws_size,
                              hipStream_t stream) {
    const float* x  = (const float*)d_in[0];
    const float* W1 = (const float*)d_in[1];
    const float* b1 = (const float*)d_in[2];
    const float* W2 = (const float*)d_in[3];
    const float* b2 = (const float*)d_in[4];
    const float* W3 = (const float*)d_in[5];
    const float* b3 = (const float*)d_in[6];
    float* out = (float*)d_out;

    dim3 grid(NB / RPB);   // 512 blocks, 2 per CU
    dim3 block(256);
    hipLaunchKernelGGL(snn_fused, grid, block, 0, stream,
                       x, W1, b1, W2, b2, W3, b3, out);
}

// Round 11
// 1137.122 us; speedup vs baseline: 1.1864x; 1.1864x over previous
//
#include <hip/hip_runtime.h>

// SNN: 3-layer LIF, 100 timesteps, ONE persistent kernel, bit-exact fp32
// numpy semantics (rounds 6/8/10 passed with absmax 0.0):
//  - LIF update: separate mul/add/sub roundings (__f*_rn, no contraction)
//  - spk1@W2: per-(row,col) k-ascending fmac chain from 0, bias AFTER.
//    Spikes as floats {0,1}; fmaf(spk,w,acc) == conditional fadd chain.
//  - x@W1 (K=2): fma(x1,w1b, round(x0*w1a)) + b1
//  - spk2@W3: fp64 tree reduce (no downstream nonlinearity)
// Round 11 vs 10: duration was pinned by LDS instruction throughput
// (409,600 broadcast ds_read_b128/CU ~ whole kernel) + exposed L2 latency,
// NOT VALU (derived VALUBusy is gfx94x-scaled; real ~35%). Changes:
//  (1) column-split threads: t -> (jj = t&127 owns cols {jj, jj+128},
//      rr = t>>7 owns rows rr*4..rr*4+3). Each spike float4 feeds 8 fmacs
//      (4k x 2cols) -> LDS reads halved. Waves rr-uniform -> still broadcast.
//  (2) #pragma unroll 4 on kg loop -> 32 W2 loads in flight, hides L2 lat.

#define NB     4096
#define NH     256
#define NSTEPS 100
#define RPB    8    // batch rows per block -> 512 blocks, 2 per CU

__global__ __launch_bounds__(256) void snn_fused(
    const float* __restrict__ x,
    const float* __restrict__ W1,
    const float* __restrict__ b1,
    const float* __restrict__ W2,
    const float* __restrict__ b2,
    const float* __restrict__ W3,
    const float* __restrict__ b3,
    float* __restrict__ out)
{
    const int t    = threadIdx.x;          // 0..255
    const int lane = t & 63;
    const int jj   = t & 127;              // output cols {jj, jj+128}
    const int rr   = t >> 7;               // row group: rows rr*4 .. rr*4+3
    const int r0   = blockIdx.x * RPB;

    __shared__ float  spks[RPB * NH];      // layer-1 spikes as floats (8 KB)
    __shared__ double red[2][4][2];        // [rr][ri][wave-pair]

    // ---- layer-1 LIF constants: thread t owns hidden unit t ----
    const float w1a = W1[t];
    const float w1b = W1[NH + t];
    const float b1t = b1[t];
    // ---- layer-2 constants: cols jj, jj+128 ----
    const float  b2lo = b2[jj];
    const float  b2hi = b2[jj + 128];
    const double w3lo = (double)W3[jj];
    const double w3hi = (double)W3[jj + 128];

    float cur1[RPB], mem1[RPB];
    #pragma unroll
    for (int r = 0; r < RPB; ++r) {
        const float x0 = x[(r0 + r) * 2 + 0];
        const float x1 = x[(r0 + r) * 2 + 1];
        cur1[r] = __fadd_rn(__fmaf_rn(x1, w1b, __fmul_rn(x0, w1a)), b1t);
        mem1[r] = 0.0f;
    }
    float mem2[4][2], spk2f[4][2];
    #pragma unroll
    for (int ri = 0; ri < 4; ++ri)
        for (int c = 0; c < 2; ++c) { mem2[ri][c] = 0.0f; spk2f[ri][c] = 0.0f; }

    const float* wp = W2 + jj;             // col base; +128 floats = +512 B imm
    const float* sp = spks + rr * 4 * NH;  // this thread's 4 rows

    for (int step = 0; step < NSTEPS; ++step) {
        // ---- layer 1 LIF (strict fp32 rounding); spikes -> LDS floats ----
        #pragma unroll
        for (int r = 0; r < RPB; ++r) {
            float m   = mem1[r];
            float rst = (m > 1.0f) ? 1.0f : 0.0f;
            m = __fsub_rn(__fadd_rn(__fmul_rn(0.9f, m), cur1[r]), rst);
            mem1[r] = m;
            spks[r * NH + t] = (m > 1.0f) ? 1.0f : 0.0f;
        }
        __syncthreads();

        // ---- layer 2 current: k-ascending fmac chains (bit-exact BLAS) ----
        float acc[4][2];
        #pragma unroll
        for (int ri = 0; ri < 4; ++ri) { acc[ri][0] = 0.0f; acc[ri][1] = 0.0f; }

        #pragma unroll 4
        for (int kg = 0; kg < NH / 4; ++kg) {
            const float* wk = wp + (kg * 4) * NH;
            float wl[4], wh[4];
            #pragma unroll
            for (int q = 0; q < 4; ++q) {
                wl[q] = wk[q * NH];          // W2[kg*4+q][jj]
                wh[q] = wk[q * NH + 128];    // W2[kg*4+q][jj+128]
            }
            #pragma unroll
            for (int ri = 0; ri < 4; ++ri) {
                const float4 s = *(const float4*)(sp + ri * NH + kg * 4);
                float a0 = acc[ri][0], a1 = acc[ri][1];
                a0 = __fmaf_rn(s.x, wl[0], a0);  a1 = __fmaf_rn(s.x, wh[0], a1);
                a0 = __fmaf_rn(s.y, wl[1], a0);  a1 = __fmaf_rn(s.y, wh[1], a1);
                a0 = __fmaf_rn(s.z, wl[2], a0);  a1 = __fmaf_rn(s.z, wh[2], a1);
                a0 = __fmaf_rn(s.w, wl[3], a0);  a1 = __fmaf_rn(s.w, wh[3], a1);
                acc[ri][0] = a0;  acc[ri][1] = a1;
            }
        }

        // ---- layer 2 LIF (bias AFTER chain, strict rounding) ----
        #pragma unroll
        for (int ri = 0; ri < 4; ++ri) {
            #pragma unroll
            for (int c = 0; c < 2; ++c) {
                float c2  = __fadd_rn(acc[ri][c], (c == 0) ? b2lo : b2hi);
                float m   = mem2[ri][c];
                float rst = (m > 1.0f) ? 1.0f : 0.0f;
                m = __fsub_rn(__fadd_rn(__fmul_rn(0.9f, m), c2), rst);
                mem2[ri][c] = m;
                spk2f[ri][c] = (m > 1.0f) ? 1.0f : 0.0f;
            }
        }
        __syncthreads();   // protect spks before next step's writes
    }

    // ---- output: out[b] = sum_j spk2[b][j]*W3[j] + b3 (fp64 tree) ----
    const int wpair = (t >> 6) & 1;   // which of the 2 waves in this rr group
    #pragma unroll
    for (int ri = 0; ri < 4; ++ri) {
        double v = (double)spk2f[ri][0] * w3lo + (double)spk2f[ri][1] * w3hi;
        #pragma unroll
        for (int off = 32; off > 0; off >>= 1)
            v += __shfl_down(v, off);   // wave64
        if (lane == 0) red[rr][ri][wpair] = v;
    }
    __syncthreads();
    if (t < RPB) {
        out[r0 + t] = (float)(red[t >> 2][t & 3][0] + red[t >> 2][t & 3][1]
                              + (double)b3[0]);
    }
}

extern "C" void kernel_launch(void* const* d_in, const int* in_sizes, int n_in,
                              void* d_out, int out_size, void* d_ws, size_t ws_size,
                              hipStream_t stream) {
    const float* x  = (const float*)d_in[0];
    const float* W1 = (const float*)d_in[1];
    const float* b1 = (const float*)d_in[2];
    const float* W2 = (const float*)d_in[3];
    const float* b2 = (const float*)d_in[4];
    const float* W3 = (const float*)d_in[5];
    const float* b3 = (const float*)d_in[6];
    float* out = (float*)d_out;

    dim3 grid(NB / RPB);   // 512 blocks, 2 per CU
    dim3 block(256);
    hipLaunchKernelGGL(snn_fused, grid, block, 0, stream,
                       x, W1, b1, W2, b2, W3, b3, out);
}